// Round 1
// 3565.617 us; speedup vs baseline: 1.8378x; 1.8378x over previous
//
#include <hip/hip_runtime.h>
#include <hip/hip_bf16.h>
#include <cstdio>

typedef __hip_bfloat16 bf16;
using s8v   = __attribute__((ext_vector_type(8))) short;
using f32x4 = __attribute__((ext_vector_type(4))) float;

#define BB    256
#define NIMG  36
#define FDIM  2048
#define LSEQ  26
#define TSTEP 25
#define ADIM  512
#define EDIM  1024
#define DDIM  1024
#define VDIM  10000
#define G4    4096
#define N3    4608    /* 4*D + A (q fused into ar-LSTM gemm) */
#define K1    5120    /* [h2|favg|e_t|h1] */
#define K2    4096    /* [aw|h1n|h2] */
#define K3    2048    /* [h1n|arh] */
#define SPLT  8       /* split-K for td/lang GEMMs */

__device__ inline float bf2f(bf16 x){ return __bfloat162float(x); }
__device__ inline bf16  f2bf(float x){ return __float2bfloat16(x); }
__device__ inline float sig_(float x){ return 1.0f/(1.0f + __expf(-x)); }
__device__ inline float tanh_(float x){ return tanhf(x); }

__device__ __forceinline__ void gl_lds16(const void* g, void* l){
  __builtin_amdgcn_global_load_lds(
      (__attribute__((address_space(1))) void*)g,
      (__attribute__((address_space(3))) void*)l, 16, 0, 0);
}

// ---------------------------------------------------------------------------
// NT GEMM: C(MxN,fp32) = A(MxK bf16 rowmajor) * Bw(NxK bf16 rowmajor)^T [+bias]
// - global_load_lds (16B) direct-to-LDS staging, double-buffered 2-phase
// - XOR slot swizzle: chunk (row,slot) holds k-chunk q = slot ^ ((row>>1)&3)
//   -> ds_read_b128 fragment reads hit all 8 bank-slots across 16 rows (2-way, free)
// - split-K over blockIdx.z (partials at C + z*M*ldc); optional A row remap
// - optional mask epilogue (t < mask[row] ? v : 0) for direct vocab->out write
// - optional nact[t] early-exit: blocks whose row range is fully inactive return
// ---------------------------------------------------------------------------
template<int BM, int BN>
__global__ __launch_bounds__(256, 2) void gemm_bt(
    const bf16* __restrict__ A, int lda,
    const bf16* __restrict__ Bw, int ldb,
    float* __restrict__ C, long ldc,
    int M, int Nreal, int Ktot, int nsplit,
    const float* __restrict__ bias,
    const int* __restrict__ rowmap,
    const int* __restrict__ mask,
    const int* __restrict__ nact, int t)
{
  constexpr int BK = 32;
  constexpr int AHALF = BM*BK;           // elements of A per buffer
  constexpr int HALF  = (BM+BN)*BK;      // elements per buffer (A then B)
  __shared__ bf16 lds[2*HALF];

  const int bn = blockIdx.x, bm = blockIdx.y, bz = blockIdx.z;
  if (nact && (long)bm*BM >= (long)nact[t]) return;

  const int tid  = threadIdx.x;
  const int lane = tid & 63;
  const int wave = tid >> 6;
  const int wr = wave & 1, wc = wave >> 1;
  constexpr int TM = BM/32, TN = BN/32;

  const int ks   = Ktot / nsplit;
  const int kbeg = bz * ks;
  const long arow0 = (long)bm*BM;
  const long bcol0 = (long)bn*BN;

  constexpr int AIT = (BM*4)/256;        // 16B chunks per thread for A tile
  constexpr int BIT = (BN*4)/256;
  const bf16* agp[AIT]; int alo[AIT];
  const bf16* bgp[BIT]; int blo[BIT];
#pragma unroll
  for (int u=0;u<AIT;u++){
    int c = tid + u*256; int r = c>>2, sl = c&3;
    int q = sl ^ ((r>>1)&3);
    long sr = arow0 + r;
    if (rowmap) sr = rowmap[sr];
    agp[u] = A + sr*(long)lda + kbeg + q*8;
    alo[u] = c*8;
  }
#pragma unroll
  for (int u=0;u<BIT;u++){
    int c = tid + u*256; int r = c>>2, sl = c&3;
    int q = sl ^ ((r>>1)&3);
    long gc = bcol0 + r;
    bgp[u] = Bw + ((gc < (long)Nreal) ? gc : 0)*(long)ldb + kbeg + q*8;
    blo[u] = AHALF + c*8;
  }

  f32x4 acc[TM][TN];
#pragma unroll
  for (int i=0;i<TM;i++)
#pragma unroll
    for (int j=0;j<TN;j++) acc[i][j] = (f32x4){0.f,0.f,0.f,0.f};

  const int m0 = lane & 15;
  const int co = (((lane>>4) ^ ((m0>>1)&3)) * 8);   // swizzled k-chunk offset
  int aoff[TM], boff[TN];
#pragma unroll
  for (int i=0;i<TM;i++) aoff[i] = (wr*(BM/2) + i*16 + m0)*BK + co;
#pragma unroll
  for (int j=0;j<TN;j++) boff[j] = AHALF + (wc*(BN/2) + j*16 + m0)*BK + co;

  // prologue: stage buf0 for k=0 (syncthreads drains vmcnt before s_barrier)
#pragma unroll
  for (int u=0;u<AIT;u++) gl_lds16(agp[u], lds + alo[u]);
#pragma unroll
  for (int u=0;u<BIT;u++) gl_lds16(bgp[u], lds + blo[u]);
  __syncthreads();

  auto phase = [&](int bc, int bp, int kc){
    const int kp = kc + BK;
    if (kp < ks) {                       // prefetch next K-tile into other buf
      bf16* Pb = lds + bp*HALF;
#pragma unroll
      for (int u=0;u<AIT;u++) gl_lds16(agp[u] + kp, Pb + alo[u]);
#pragma unroll
      for (int u=0;u<BIT;u++) gl_lds16(bgp[u] + kp, Pb + blo[u]);
    }
    const bf16* Lb = lds + bc*HALF;
    s8v afr[TM], bfr[TN];
#pragma unroll
    for (int i=0;i<TM;i++) afr[i] = *(const s8v*)(Lb + aoff[i]);
#pragma unroll
    for (int j=0;j<TN;j++) bfr[j] = *(const s8v*)(Lb + boff[j]);
#pragma unroll
    for (int i=0;i<TM;i++)
#pragma unroll
      for (int j=0;j<TN;j++)
        acc[i][j] = __builtin_amdgcn_mfma_f32_16x16x32_bf16(afr[i], bfr[j], acc[i][j], 0, 0, 0);
    __syncthreads();                     // drains vmcnt(0): prefetch landed
  };
  for (int kc = 0; kc < ks; kc += 2*BK) {   // ks/BK is even for all call sites
    phase(0, 1, kc);
    phase(1, 0, kc + BK);
  }

  float* Cz = C + (long)bz * (long)M * ldc;
  const int rq = lane >> 4;
#pragma unroll
  for (int i=0;i<TM;i++){
    long row = arow0 + wr*(BM/2) + i*16 + rq*4;
#pragma unroll
    for (int j=0;j<TN;j++){
      long col = bcol0 + wc*(BN/2) + j*16 + m0;
      if (col < (long)Nreal) {
        float bv = (bias != nullptr && bz == 0) ? bias[col] : 0.f;
#pragma unroll
        for (int r=0;r<4;r++){
          float v = acc[i][j][r] + bv;
          if (mask) v = (t < mask[row + r]) ? v : 0.f;
          Cz[(row + r)*ldc + col] = v;
        }
      }
    }
  }
}

// ---------------------------------------------------------------------------
// Setup kernels
// ---------------------------------------------------------------------------
__global__ __launch_bounds__(256) void sort_kernel(
    const int* __restrict__ sizesp, int* __restrict__ order,
    int* __restrict__ dec, float* __restrict__ bszf, int* __restrict__ nact,
    int* __restrict__ rowmap)
{
  __shared__ int ssz[BB], so[BB], sd[BB];
  int b = threadIdx.x;
  ssz[b] = sizesp[b];
  __syncthreads();
  int s = ssz[b];
  int rank = 0;
  for (int j=0;j<BB;j++){
    int sj = ssz[j];
    rank += (sj > s) || (sj == s && j < b);
  }
  so[rank] = b;
  sd[rank] = s - 1;
  __syncthreads();
  order[b] = so[b];
  dec[b]   = sd[b];
  if (b < TSTEP){
    int c=0;
    for (int j=0;j<BB;j++) c += (sd[j] > b);
    bszf[b] = (float)(c > 0 ? c : 1);
    nact[b] = c;                     // active prefix length at step b (>=1)
  }
  for (int r=b; r<BB*NIMG; r+=BB) rowmap[r] = so[r/NIMG]*NIMG + (r%NIMG);
}

__global__ __launch_bounds__(256) void zero_f32(float* __restrict__ pz, long n){
  long i = (long)blockIdx.x*256 + threadIdx.x;
  if (i < n) pz[i] = 0.f;
}

// fp32 -> bf16 convert, 8 elements/thread (n must be a multiple of 8)
__global__ __launch_bounds__(256) void f2b_kernel(
    const float* __restrict__ s, bf16* __restrict__ d, long n)
{
  long i = ((long)blockIdx.x*256 + threadIdx.x)*8;
  if (i >= n) return;
  float4 a = *(const float4*)(s+i);
  float4 b = *(const float4*)(s+i+4);
  bf16 t[8] = {f2bf(a.x),f2bf(a.y),f2bf(a.z),f2bf(a.w),
               f2bf(b.x),f2bf(b.y),f2bf(b.z),f2bf(b.w)};
  *(uint4*)(d+i) = *(uint4*)t;
}

__global__ __launch_bounds__(256) void init_xcat(
    bf16* __restrict__ x1, bf16* __restrict__ x2, bf16* __restrict__ x3)
{
  int idx = blockIdx.x*256 + threadIdx.x;   // b*D + d
  int b = idx >> 10, d = idx & 1023;
  bf16 z = f2bf(0.f);
  x1[(long)b*K1 + d]        = z;   // h2 carry slot
  x1[(long)b*K1 + 4096 + d] = z;   // h1 carry slot
  x2[(long)b*K2 + 3072 + d] = z;   // h2 carry slot
  x3[(long)b*K3 + 1024 + d] = z;   // arh carry slot
}

__global__ __launch_bounds__(256) void favg_kernel(
    const float* __restrict__ feats, const int* __restrict__ order,
    bf16* __restrict__ x1)
{
  int idx = blockIdx.x*256 + threadIdx.x;   // b*F + f
  int b = idx >> 11, f = idx & 2047;
  const float* fb = feats + (long)order[b]*NIMG*FDIM + f;
  float s = 0.f;
#pragma unroll 4
  for (int n=0;n<NIMG;n++) s += fb[n*FDIM];
  x1[(long)b*K1 + 1024 + f] = f2bf(s * (1.0f/36.0f));
}

// concat fp32 sources [rows x k1 | rows x k2] -> bf16 dst, 8 elems/thread
__global__ __launch_bounds__(256) void concat2_f(
    bf16* __restrict__ dst, const float* __restrict__ s1, int k1,
    const float* __restrict__ s2, int k2, int rows)
{
  long nch = (long)rows*(k1+k2)/8;
  long c = (long)blockIdx.x*256 + threadIdx.x;
  if (c >= nch) return;
  long e = c*8;
  int ld = k1+k2;
  long r = e / ld; int col = (int)(e % ld);
  const float* src = (col < k1) ? (s1 + r*(long)k1 + col) : (s2 + r*(long)k2 + (col - k1));
  float4 a = *(const float4*)src;
  float4 b = *(const float4*)(src+4);
  bf16 t[8] = {f2bf(a.x),f2bf(a.y),f2bf(a.z),f2bf(a.w),
               f2bf(b.x),f2bf(b.y),f2bf(b.z),f2bf(b.w)};
  *(uint4*)(dst + e) = *(uint4*)t;
}

__global__ __launch_bounds__(256) void w3_attd_f(
    bf16* __restrict__ w3, const float* __restrict__ attd_w)
{
  long c = (long)blockIdx.x*256 + threadIdx.x;   // 512*2048/8 chunks
  long e = c*8;
  long r = e / 2048; int col = (int)(e % 2048);
  bf16 t[8];
  if (col < 1024){
    const float* src = attd_w + r*1024 + col;
    float4 a = *(const float4*)src;
    float4 b = *(const float4*)(src+4);
    t[0]=f2bf(a.x); t[1]=f2bf(a.y); t[2]=f2bf(a.z); t[3]=f2bf(a.w);
    t[4]=f2bf(b.x); t[5]=f2bf(b.y); t[6]=f2bf(b.z); t[7]=f2bf(b.w);
  } else {
    bf16 z = f2bf(0.f);
#pragma unroll
    for (int u=0;u<8;u++) t[u]=z;
  }
  *(uint4*)(w3 + (4096 + r)*2048 + col) = *(uint4*)t;
}

__global__ __launch_bounds__(256) void attb_kernel(
    const float* __restrict__ a, const float* __restrict__ b, float* __restrict__ o)
{
  int i = blockIdx.x*256 + threadIdx.x;
  if (i < ADIM) o[i] = a[i] + b[i];
}

// ---------------------------------------------------------------------------
// Per-step kernels (all early-exit on the inactive suffix via nact[t])
// ---------------------------------------------------------------------------
__global__ __launch_bounds__(256) void embed_kernel(
    const int* __restrict__ seqs, const int* __restrict__ order,
    const float* __restrict__ emb, int t, const int* __restrict__ nact,
    bf16* __restrict__ x1)
{
  int idx = blockIdx.x*256 + threadIdx.x;   // b*E + e
  int b = idx >> 10, e = idx & 1023;
  if (b >= nact[t]) return;
  int tok = seqs[order[b]*LSEQ + t];
  x1[(long)b*K1 + 3072 + e] = f2bf(emb[(long)tok*EDIM + e]);
}

__global__ __launch_bounds__(256) void gates1_kernel(
    const float* __restrict__ g, const float* __restrict__ bias,
    const float* __restrict__ h_old, float* __restrict__ h_new,
    float* __restrict__ c, const int* __restrict__ nact, int t,
    bf16* __restrict__ x1, bf16* __restrict__ x2, bf16* __restrict__ x3)
{
  int idx = blockIdx.x*256 + threadIdx.x;
  int b = idx >> 10, d = idx & 1023;
  if (b >= nact[t]) { h_new[idx] = h_old[idx]; return; }  // ping-pong carry copy
  float gi=0,gf=0,gg=0,go=0;
#pragma unroll
  for (int z=0; z<SPLT; z++){
    const float* gz = g + (long)z*BB*G4 + (long)b*G4;
    gi += gz[d]; gf += gz[d+1024]; gg += gz[d+2048]; go += gz[d+3072];
  }
  gi += bias[d]; gf += bias[d+1024]; gg += bias[d+2048]; go += bias[d+3072];
  float cn = sig_(gf)*c[idx] + sig_(gi)*tanh_(gg);
  float hn = sig_(go)*tanh_(cn);
  h_new[idx] = hn;
  c[idx] = cn;
  x1[(long)b*K1 + 4096 + d] = f2bf(hn);   // h1 carry for next-step td GEMM
  x2[(long)b*K2 + 2048 + d] = f2bf(hn);   // h1n into lang GEMM
  x3[(long)b*K3 + d]        = f2bf(hn);   // h1n into ar/q GEMM
}

__global__ __launch_bounds__(256) void gates2_kernel(
    const float* __restrict__ g, const float* __restrict__ bias,
    float* __restrict__ h2s, float* __restrict__ c2s,
    const int* __restrict__ nact, int t,
    bf16* __restrict__ h2n_bf, bf16* __restrict__ x1, bf16* __restrict__ x2)
{
  int idx = blockIdx.x*256 + threadIdx.x;
  int b = idx >> 10, d = idx & 1023;
  if (b >= nact[t]) return;               // in-place state: nothing to copy
  float gi=0,gf=0,gg=0,go=0;
#pragma unroll
  for (int z=0; z<SPLT; z++){
    const float* gz = g + (long)z*BB*G4 + (long)b*G4;
    gi += gz[d]; gf += gz[d+1024]; gg += gz[d+2048]; go += gz[d+3072];
  }
  gi += bias[d]; gf += bias[d+1024]; gg += bias[d+2048]; go += bias[d+3072];
  float cn = sig_(gf)*c2s[idx] + sig_(gi)*tanh_(gg);
  float hn = sig_(go)*tanh_(cn);
  h2s[idx] = hn;
  c2s[idx] = cn;
  h2n_bf[idx] = f2bf(hn);                 // -> vocab GEMM (masked in epilogue)
  x1[(long)b*K1 + d]        = f2bf(hn);   // h2 carry for next-step td GEMM
  x2[(long)b*K2 + 3072 + d] = f2bf(hn);   // h2 carry for next-step lang GEMM
}

__global__ __launch_bounds__(256) void gates3_kernel(
    const float* __restrict__ g, const float* __restrict__ bias,
    float* __restrict__ arh, float* __restrict__ arc,
    const int* __restrict__ nact, int t,
    bf16* __restrict__ arhn_bf, bf16* __restrict__ x3)
{
  int idx = blockIdx.x*256 + threadIdx.x;
  int b = idx >> 10, d = idx & 1023;
  if (b >= nact[t]) return;
  float gi=0,gf=0,gg=0,go=0;
#pragma unroll
  for (int z=0; z<4; z++){
    const float* gz = g + (long)z*BB*N3 + (long)b*N3;
    gi += gz[d]; gf += gz[d+1024]; gg += gz[d+2048]; go += gz[d+3072];
  }
  gi += bias[d]; gf += bias[d+1024]; gg += bias[d+2048]; go += bias[d+3072];
  float cn = sig_(gf)*arc[idx] + sig_(gi)*tanh_(gg);
  float hn = sig_(go)*tanh_(cn);
  arh[idx] = hn;
  arc[idx] = cn;
  arhn_bf[idx] = f2bf(hn);                      // -> arl GEMM
  x3[(long)b*K3 + 1024 + d] = f2bf(hn);         // carry for next step
}

__global__ __launch_bounds__(256) void scores_kernel(
    const float* __restrict__ g3,          // q at cols [4096,4608), 4 split-K partials
    const float* __restrict__ imgatt,      // (B*NIMG) x A fp32 (attf_b+attd_b folded)
    const float* __restrict__ att_w, const float* __restrict__ att_b,
    const int* __restrict__ nact, int t,
    float* __restrict__ scores)
{
  int gw = blockIdx.x*4 + (threadIdx.x >> 6);
  if (gw >= BB*NIMG) return;
  int b = gw / NIMG;
  if (b >= nact[t]) return;
  int lane = threadIdx.x & 63;
  const float* q0 = g3 + (long)b*N3 + 4096;
  const float* ia = imgatt + (long)gw*ADIM;
  float s = 0.f;
#pragma unroll
  for (int u=0; u<8; u++){
    int a = u*64 + lane;
    float v = q0[a] + q0[(long)BB*N3 + a] + q0[2L*BB*N3 + a] + q0[3L*BB*N3 + a] + ia[a];
    v = fmaxf(v, 0.f);
    s += v * att_w[a];
  }
  for (int off=32; off; off>>=1) s += __shfl_down(s, off);
  if (lane == 0) scores[gw] = s + att_b[0];
}

__global__ __launch_bounds__(256) void attn_kernel(
    const float* __restrict__ scores, const bf16* __restrict__ feats_bf,
    const int* __restrict__ order, const int* __restrict__ nact, int t,
    bf16* __restrict__ x2)
{
  int b = blockIdx.x;
  if (b >= nact[t]) return;
  __shared__ float alpha[NIMG];
  int tid = threadIdx.x;
  if (tid < 64) {
    float v = (tid < NIMG) ? scores[b*NIMG + tid] : -1e30f;
    float m = v;
    for (int off=32; off; off>>=1) m = fmaxf(m, __shfl_down(m, off));
    m = __shfl(m, 0);
    float e = (tid < NIMG) ? __expf(v - m) : 0.f;
    float sum = e;
    for (int off=32; off; off>>=1) sum += __shfl_down(sum, off);
    sum = __shfl(sum, 0);
    if (tid < NIMG) alpha[tid] = e / sum;
  }
  __syncthreads();
  const bf16* fsb = feats_bf + (long)order[b]*NIMG*FDIM;
  int f0 = tid*8;                           // 256*8 == 2048
  float s[8] = {0.f,0.f,0.f,0.f,0.f,0.f,0.f,0.f};
#pragma unroll 4
  for (int n=0; n<NIMG; n++){
    float al = alpha[n];
    bf16 v[8]; *(s8v*)v = *(const s8v*)(fsb + (long)n*FDIM + f0);
#pragma unroll
    for (int u=0;u<8;u++) s[u] += al * bf2f(v[u]);
  }
  bf16 o[8];
#pragma unroll
  for (int u=0;u<8;u++) o[u] = f2bf(s[u]);
  *(uint4*)(x2 + (long)b*K2 + f0) = *(uint4*)o;
}

__global__ __launch_bounds__(256) void loss_kernel(
    const float* __restrict__ arl_out,   // 4 split-K partials; bias in z==0
    const float* __restrict__ h_old,     // prev_h1 == h1 entering this step
    const int* __restrict__ nact, const float* __restrict__ bszf,
    int t, float* __restrict__ loss)
{
  if (t == 0) return;
  int b = blockIdx.x;
  if (b >= nact[t]) return;
  const long SDL = (long)BB*DDIM;
  float s = 0.f;
  for (int d = threadIdx.x; d < DDIM; d += 256) {
    long i = (long)b*DDIM + d;
    float v = arl_out[i] + arl_out[SDL + i] + arl_out[2*SDL + i] + arl_out[3*SDL + i]
            - h_old[i];
    s += v*v;
  }
  __shared__ float red[4];
  for (int off=32; off; off>>=1) s += __shfl_down(s, off);
  if ((threadIdx.x & 63) == 0) red[threadIdx.x >> 6] = s;
  __syncthreads();
  if (threadIdx.x == 0) {
    float tot = red[0]+red[1]+red[2]+red[3];
    atomicAdd(loss, tot * (0.005f / bszf[t]));
  }
}

__global__ void finalize_kernel(const float* __restrict__ loss, float* __restrict__ out){
  if (threadIdx.x == 0) out[(long)BB*TSTEP*VDIM] = *loss;
}

// ---------------------------------------------------------------------------
extern "C" void kernel_launch(void* const* d_in, const int* in_sizes, int n_in,
                              void* d_out, int out_size, void* d_ws, size_t ws_size,
                              hipStream_t stream) {
  const float* feats    = (const float*)d_in[0];
  const int*   seqs     = (const int*)d_in[1];
  const int*   sizesp   = (const int*)d_in[2];
  const float* emb      = (const float*)d_in[3];
  const float* td_wih   = (const float*)d_in[4];
  const float* td_whh   = (const float*)d_in[5];
  const float* td_b     = (const float*)d_in[6];
  const float* lang_wih = (const float*)d_in[7];
  const float* lang_whh = (const float*)d_in[8];
  const float* lang_b   = (const float*)d_in[9];
  const float* attf_w   = (const float*)d_in[10];
  const float* attf_b   = (const float*)d_in[11];
  const float* attd_w   = (const float*)d_in[12];
  const float* attd_b   = (const float*)d_in[13];
  const float* att_w    = (const float*)d_in[14];
  const float* att_b    = (const float*)d_in[15];
  const float* out_w    = (const float*)d_in[16];
  const float* out_b    = (const float*)d_in[17];
  const float* ar_wih   = (const float*)d_in[18];
  const float* ar_whh   = (const float*)d_in[19];
  const float* ar_b     = (const float*)d_in[20];
  const float* arl_w    = (const float*)d_in[21];
  const float* arl_b    = (const float*)d_in[22];
  float* out = (float*)d_out;

  char* p = (char*)d_ws;
  auto alloc = [&](size_t n) -> void* {
    void* r = (void*)p; p += ((n + 255) & ~(size_t)255); return r;
  };
  const long SD = (long)BB*DDIM;   // 262144 floats per state

  int*   order    = (int*)  alloc(BB*4);
  int*   dec      = (int*)  alloc(BB*4);
  float* bszf     = (float*)alloc(TSTEP*4);
  int*   nact     = (int*)  alloc(TSTEP*4);
  int*   rowmap   = (int*)  alloc(BB*NIMG*4);
  float* stateblk = (float*)alloc((7*SD + 64)*4);  // h1A,h1B,c1,h2,c2,arh,arc,loss
  bf16*  W1       = (bf16*) alloc((size_t)G4*K1*2);
  bf16*  W2       = (bf16*) alloc((size_t)G4*K2*2);
  bf16*  W3       = (bf16*) alloc((size_t)N3*K3*2);
  bf16*  feats_bf = (bf16*) alloc((size_t)BB*NIMG*FDIM*2);
  bf16*  attf_bf  = (bf16*) alloc((size_t)ADIM*FDIM*2);
  bf16*  outw_bf  = (bf16*) alloc((size_t)VDIM*DDIM*2);
  bf16*  arlw_bf  = (bf16*) alloc((size_t)DDIM*DDIM*2);
  bf16*  xcat1    = (bf16*) alloc((size_t)BB*K1*2);
  bf16*  xcat2    = (bf16*) alloc((size_t)BB*K2*2);
  bf16*  xcat3    = (bf16*) alloc((size_t)BB*K3*2);
  bf16*  h2n_bf   = (bf16*) alloc((size_t)BB*DDIM*2);
  bf16*  arhn_bf  = (bf16*) alloc((size_t)BB*DDIM*2);
  float* g12      = (float*)alloc((size_t)SPLT*BB*G4*4);  // td/lang partials
  float* arl_out  = (float*)alloc((size_t)4*BB*DDIM*4);   // arl partials
  float* imgatt   = (float*)alloc((size_t)BB*NIMG*ADIM*4);
  float* scorebuf = (float*)alloc((size_t)BB*NIMG*4);
  float* attb     = (float*)alloc((size_t)ADIM*4);
  float* g3       = g12;   // alias: ar GEMM runs strictly between gates1 and lang GEMM
                           // (4*BB*N3 floats <= SPLT*BB*G4 floats)

  size_t need = (size_t)(p - (char*)d_ws);
  if (need > ws_size) {
    fprintf(stderr, "kernel_launch: ws too small: need %zu have %zu\n", need, ws_size);
    return;
  }

  float* h1A = stateblk;
  float* h1B = stateblk + SD;
  float* c1  = stateblk + 2*SD;
  float* h2s = stateblk + 3*SD;
  float* c2s = stateblk + 4*SD;
  float* arh = stateblk + 5*SD;
  float* arc = stateblk + 6*SD;
  float* loss = stateblk + 7*SD;

  // ---- setup ----
  sort_kernel<<<1, 256, 0, stream>>>(sizesp, order, dec, bszf, nact, rowmap);
  long nz = 7*SD + 64;
  zero_f32<<<(int)((nz + 255)/256), 256, 0, stream>>>(stateblk, nz);
  long nout = (long)BB*TSTEP*VDIM;   // pre-zero: vocab GEMM skips inactive blocks
  zero_f32<<<(int)((nout + 255)/256), 256, 0, stream>>>(out, nout);
  init_xcat<<<1024, 256, 0, stream>>>(xcat1, xcat2, xcat3);
  favg_kernel<<<2048, 256, 0, stream>>>(feats, order, xcat1);
  f2b_kernel<<<9216, 256, 0, stream>>>(feats,  feats_bf, (long)BB*NIMG*FDIM);
  f2b_kernel<<< 512, 256, 0, stream>>>(attf_w, attf_bf,  (long)ADIM*FDIM);
  f2b_kernel<<<5000, 256, 0, stream>>>(out_w,  outw_bf,  (long)VDIM*DDIM);
  f2b_kernel<<< 512, 256, 0, stream>>>(arl_w,  arlw_bf,  (long)DDIM*DDIM);
  concat2_f<<<10240, 256, 0, stream>>>(W1, td_wih, 4096, td_whh, 1024, 4096);
  concat2_f<<< 8192, 256, 0, stream>>>(W2, lang_wih, 3072, lang_whh, 1024, 4096);
  concat2_f<<< 4096, 256, 0, stream>>>(W3, ar_wih, 1024, ar_whh, 1024, 4096);
  w3_attd_f<<<512, 256, 0, stream>>>(W3, attd_w);
  attb_kernel<<<2, 256, 0, stream>>>(attf_b, attd_b, attb);
  // img_att = fs @ attf_w^T (fs via rowmap gather) + (attf_b + attd_b)
  gemm_bt<128,128><<<dim3(4,72,1), 256, 0, stream>>>(
      feats_bf, FDIM, attf_bf, FDIM, imgatt, (long)ADIM, BB*NIMG, ADIM, FDIM, 1,
      attb, rowmap, nullptr, nullptr, 0);

  // ---- recurrence ----
  for (int t = 0; t < TSTEP; t++) {
    float* h1old = (t & 1) ? h1B : h1A;
    float* h1new = (t & 1) ? h1A : h1B;

    embed_kernel<<<1024, 256, 0, stream>>>(seqs, order, emb, t, nact, xcat1);

    gemm_bt<128,128><<<dim3(32,2,SPLT), 256, 0, stream>>>(   // td gates
        xcat1, K1, W1, K1, g12, (long)G4, BB, G4, K1, SPLT,
        nullptr, nullptr, nullptr, nact, t);
    gates1_kernel<<<1024, 256, 0, stream>>>(
        g12, td_b, h1old, h1new, c1, nact, t, xcat1, xcat2, xcat3);

    gemm_bt<128,128><<<dim3(36,2,4), 256, 0, stream>>>(      // ar gates + q (fused)
        xcat3, K3, W3, K3, g3, (long)N3, BB, N3, K3, 4,
        nullptr, nullptr, nullptr, nact, t);
    gates3_kernel<<<1024, 256, 0, stream>>>(
        g3, ar_b, arh, arc, nact, t, arhn_bf, xcat3);

    scores_kernel<<<2304, 256, 0, stream>>>(
        g3, imgatt, att_w, att_b, nact, t, scorebuf);
    attn_kernel<<<256, 256, 0, stream>>>(scorebuf, feats_bf, order, nact, t, xcat2);

    gemm_bt<128,128><<<dim3(32,2,SPLT), 256, 0, stream>>>(   // lang gates
        xcat2, K2, W2, K2, g12, (long)G4, BB, G4, K2, SPLT,
        nullptr, nullptr, nullptr, nact, t);
    gates2_kernel<<<1024, 256, 0, stream>>>(
        g12, lang_b, h2s, c2s, nact, t, h2n_bf, xcat1, xcat2);

    gemm_bt<64,64><<<dim3(16,4,4), 256, 0, stream>>>(        // arl projection
        arhn_bf, DDIM, arlw_bf, DDIM, arl_out, (long)DDIM, BB, DDIM, DDIM, 4,
        arl_b, nullptr, nullptr, nact, t);
    loss_kernel<<<256, 256, 0, stream>>>(arl_out, h1old, nact, bszf, t, loss);

    gemm_bt<128,64><<<dim3(157,2,1), 256, 0, stream>>>(      // vocab -> out (masked)
        h2n_bf, DDIM, outw_bf, DDIM, out + (long)t*VDIM, (long)TSTEP*VDIM,
        BB, VDIM, DDIM, 1, out_b, nullptr, dec, nact, t);
  }

  finalize_kernel<<<1, 64, 0, stream>>>(loss, out);
}

// Round 2
// 2941.876 us; speedup vs baseline: 2.2275x; 1.2120x over previous
//
#include <hip/hip_runtime.h>
#include <hip/hip_bf16.h>
#include <cstdio>

typedef __hip_bfloat16 bf16;
using s8v   = __attribute__((ext_vector_type(8))) short;
using f32x4 = __attribute__((ext_vector_type(4))) float;

#define BB    256
#define NIMG  36
#define FDIM  2048
#define LSEQ  26
#define TSTEP 25
#define ADIM  512
#define EDIM  1024
#define DDIM  1024
#define VDIM  10000
#define G4    4096
#define N3    4608    /* 4*D + A (q fused into ar-LSTM gemm) */
#define K1    5120    /* [h2|favg|e_t|h1] */
#define K2    4096    /* [aw|h1n|h2] */
#define K3    2048    /* [h1n|arh] */
#define SPLT  4       /* split-K for td/lang GEMMs */
#define SPLTA 2       /* split-K for arl GEMM */

__device__ inline float bf2f(bf16 x){ return __bfloat162float(x); }
__device__ inline bf16  f2bf(float x){ return __float2bfloat16(x); }
__device__ inline float sig_(float x){ return 1.0f/(1.0f + __expf(-x)); }
__device__ inline float tanh_(float x){ return tanhf(x); }

__device__ __forceinline__ void gl_lds16(const void* g, void* l){
  __builtin_amdgcn_global_load_lds(
      (__attribute__((address_space(1))) void*)g,
      (__attribute__((address_space(3))) void*)l, 16, 0, 0);
}

// ---------------------------------------------------------------------------
// Dual NT GEMM dispatch: blocks [0,nblk0) run arg-set a0, the rest a1.
// C(MxN,fp32) = A(MxK bf16 rowmajor) * Bw(NxK bf16 rowmajor)^T [+bias]
// - global_load_lds (16B) direct-to-LDS, 3-buffer depth-2 pipeline with
//   counted s_waitcnt vmcnt(4) + raw s_barrier (loads stay in flight across
//   barriers; never drain to 0 in the main loop)
// - XOR slot swizzle: chunk (row,slot) holds k-chunk q = slot ^ ((row>>1)&3)
// - split-K over bz (partials at C + z*M*ldc); optional A row remap
// - optional mask epilogue (tt < mask[row] ? v : 0) for direct vocab->out
// - optional nact[tt] early-exit for inactive row-blocks
// ---------------------------------------------------------------------------
struct GArgs {
  const bf16* A; const bf16* Bw; float* C;
  const float* bias; const int* rowmap; const int* mask;
  long ldc;
  int lda, ldb, M, Nreal, Ktot, nsplit, nbx, nby, tt, use_nact;
};

template<int BM, int BN>
__global__ __launch_bounds__(256, 2) void gemm_dual(
    GArgs a0, GArgs a1, int nblk0, const int* __restrict__ nact)
{
  constexpr int BK = 32;
  constexpr int AHALF = BM*BK;
  constexpr int HALF  = (BM+BN)*BK;
  __shared__ bf16 lds[3*HALF];

  int id = blockIdx.x;
  GArgs g = (id < nblk0) ? a0 : a1;
  if (id >= nblk0) id -= nblk0;
  const int bz  = id / (g.nbx * g.nby);
  const int rem = id - bz*(g.nbx*g.nby);
  const int bm  = rem / g.nbx;
  const int bn  = rem - bm*g.nbx;
  if (g.use_nact && (long)bm*BM >= (long)nact[g.tt]) return;

  const int tid  = threadIdx.x;
  const int lane = tid & 63;
  const int wave = tid >> 6;
  const int wr = wave & 1, wc = wave >> 1;
  constexpr int TM = BM/32, TN = BN/32;

  const int ks   = g.Ktot / g.nsplit;
  const int kbeg = bz * ks;
  const long arow0 = (long)bm*BM;
  const long bcol0 = (long)bn*BN;

  constexpr int AIT = (BM*4)/256;        // 16B chunks per thread for A tile
  constexpr int BIT = (BN*4)/256;
  const bf16* agp[AIT]; int alo[AIT];
  const bf16* bgp[BIT]; int blo[BIT];
#pragma unroll
  for (int u=0;u<AIT;u++){
    int c = tid + u*256; int r = c>>2, sl = c&3;
    int q = sl ^ ((r>>1)&3);
    long sr = arow0 + r;
    if (g.rowmap) sr = g.rowmap[sr];
    agp[u] = g.A + sr*(long)g.lda + kbeg + q*8;
    alo[u] = c*8;
  }
#pragma unroll
  for (int u=0;u<BIT;u++){
    int c = tid + u*256; int r = c>>2, sl = c&3;
    int q = sl ^ ((r>>1)&3);
    long gc = bcol0 + r;
    bgp[u] = g.Bw + ((gc < (long)g.Nreal) ? gc : 0)*(long)g.ldb + kbeg + q*8;
    blo[u] = AHALF + c*8;
  }

  f32x4 acc[TM][TN];
#pragma unroll
  for (int i=0;i<TM;i++)
#pragma unroll
    for (int j=0;j<TN;j++) acc[i][j] = (f32x4){0.f,0.f,0.f,0.f};

  const int m0 = lane & 15;
  const int co = (((lane>>4) ^ ((m0>>1)&3)) * 8);   // swizzled k-chunk offset
  int aoff[TM], boff[TN];
#pragma unroll
  for (int i=0;i<TM;i++) aoff[i] = (wr*(BM/2) + i*16 + m0)*BK + co;
#pragma unroll
  for (int j=0;j<TN;j++) boff[j] = AHALF + (wc*(BN/2) + j*16 + m0)*BK + co;

  auto stage = [&](int koff, int lbase){
#pragma unroll
    for (int u=0;u<AIT;u++) gl_lds16(agp[u] + koff, lds + lbase + alo[u]);
#pragma unroll
    for (int u=0;u<BIT;u++) gl_lds16(bgp[u] + koff, lds + lbase + blo[u]);
  };
  auto compute = [&](int lbase){
    const bf16* Lb = lds + lbase;
    s8v afr[TM], bfr[TN];
#pragma unroll
    for (int i=0;i<TM;i++) afr[i] = *(const s8v*)(Lb + aoff[i]);
#pragma unroll
    for (int j=0;j<TN;j++) bfr[j] = *(const s8v*)(Lb + boff[j]);
#pragma unroll
    for (int i=0;i<TM;i++)
#pragma unroll
      for (int j=0;j<TN;j++)
        acc[i][j] = __builtin_amdgcn_mfma_f32_16x16x32_bf16(afr[i], bfr[j], acc[i][j], 0, 0, 0);
  };

  const int nt = ks / BK;                // >= 16 for all call sites
  // prologue: T0 -> buf0, T1 -> buf1 (stay in flight; no drain)
  stage(0, 0);
  stage(BK, HALF);
  int bc = 0;
  for (int k = 0; k < nt-1; ++k){
    __builtin_amdgcn_sched_barrier(0);
    asm volatile("s_waitcnt vmcnt(%0)" :: "n"(AIT+BIT) : "memory");  // Tk landed
    __builtin_amdgcn_s_barrier();        // all waves have Tk; buf (k+2)%3 free
    __builtin_amdgcn_sched_barrier(0);
    if (k+2 < nt){
      int bp = bc+2; if (bp >= 3) bp -= 3;
      stage((k+2)*BK, bp*HALF);
    }
    compute(bc*HALF);
    bc = (bc+1 == 3) ? 0 : bc+1;
  }
  __builtin_amdgcn_sched_barrier(0);
  asm volatile("s_waitcnt vmcnt(0)" ::: "memory");
  __builtin_amdgcn_s_barrier();
  __builtin_amdgcn_sched_barrier(0);
  compute(bc*HALF);

  float* Cz = g.C + (long)bz * (long)g.M * g.ldc;
  const int rq = lane >> 4;
#pragma unroll
  for (int i=0;i<TM;i++){
    long row = arow0 + wr*(BM/2) + i*16 + rq*4;
#pragma unroll
    for (int j=0;j<TN;j++){
      long col = bcol0 + wc*(BN/2) + j*16 + m0;
      if (col < (long)g.Nreal) {
        float bv = (g.bias != nullptr && bz == 0) ? g.bias[col] : 0.f;
#pragma unroll
        for (int r=0;r<4;r++){
          float v = acc[i][j][r] + bv;
          if (g.mask) v = (g.tt < g.mask[row + r]) ? v : 0.f;
          Cz[(row + r)*g.ldc + col] = v;
        }
      }
    }
  }
}

// ---------------------------------------------------------------------------
// Setup kernels
// ---------------------------------------------------------------------------
__global__ __launch_bounds__(256) void sort_kernel(
    const int* __restrict__ sizesp, int* __restrict__ order,
    int* __restrict__ dec, float* __restrict__ bszf, int* __restrict__ nact,
    int* __restrict__ rowmap)
{
  __shared__ int ssz[BB], so[BB], sd[BB];
  int b = threadIdx.x;
  ssz[b] = sizesp[b];
  __syncthreads();
  int s = ssz[b];
  int rank = 0;
  for (int j=0;j<BB;j++){
    int sj = ssz[j];
    rank += (sj > s) || (sj == s && j < b);
  }
  so[rank] = b;
  sd[rank] = s - 1;
  __syncthreads();
  order[b] = so[b];
  dec[b]   = sd[b];
  if (b < TSTEP){
    int c=0;
    for (int j=0;j<BB;j++) c += (sd[j] > b);
    bszf[b] = (float)(c > 0 ? c : 1);
    nact[b] = c;                     // active prefix length at step b (>=1)
  }
  for (int r=b; r<BB*NIMG; r+=BB) rowmap[r] = so[r/NIMG]*NIMG + (r%NIMG);
}

__global__ __launch_bounds__(256) void zero_f32(float* __restrict__ pz, long n){
  long i = (long)blockIdx.x*256 + threadIdx.x;
  if (i < n) pz[i] = 0.f;
}

__global__ __launch_bounds__(256) void f2b_kernel(
    const float* __restrict__ s, bf16* __restrict__ d, long n)
{
  long i = ((long)blockIdx.x*256 + threadIdx.x)*8;
  if (i >= n) return;
  float4 a = *(const float4*)(s+i);
  float4 b = *(const float4*)(s+i+4);
  bf16 t[8] = {f2bf(a.x),f2bf(a.y),f2bf(a.z),f2bf(a.w),
               f2bf(b.x),f2bf(b.y),f2bf(b.z),f2bf(b.w)};
  *(uint4*)(d+i) = *(uint4*)t;
}

__global__ __launch_bounds__(256) void init_xcat(
    bf16* __restrict__ x1, bf16* __restrict__ x2, bf16* __restrict__ x3)
{
  int idx = blockIdx.x*256 + threadIdx.x;   // b*D + d
  int b = idx >> 10, d = idx & 1023;
  bf16 z = f2bf(0.f);
  x1[(long)b*K1 + d]        = z;   // h2 carry slot
  x1[(long)b*K1 + 4096 + d] = z;   // h1 carry slot
  x2[(long)b*K2 + 3072 + d] = z;   // h2 carry slot
  x3[(long)b*K3 + 1024 + d] = z;   // arh carry slot
}

__global__ __launch_bounds__(256) void favg_kernel(
    const float* __restrict__ feats, const int* __restrict__ order,
    bf16* __restrict__ x1)
{
  int idx = blockIdx.x*256 + threadIdx.x;   // b*F + f
  int b = idx >> 11, f = idx & 2047;
  const float* fb = feats + (long)order[b]*NIMG*FDIM + f;
  float s = 0.f;
#pragma unroll 4
  for (int n=0;n<NIMG;n++) s += fb[n*FDIM];
  x1[(long)b*K1 + 1024 + f] = f2bf(s * (1.0f/36.0f));
}

__global__ __launch_bounds__(256) void concat2_f(
    bf16* __restrict__ dst, const float* __restrict__ s1, int k1,
    const float* __restrict__ s2, int k2, int rows)
{
  long nch = (long)rows*(k1+k2)/8;
  long c = (long)blockIdx.x*256 + threadIdx.x;
  if (c >= nch) return;
  long e = c*8;
  int ld = k1+k2;
  long r = e / ld; int col = (int)(e % ld);
  const float* src = (col < k1) ? (s1 + r*(long)k1 + col) : (s2 + r*(long)k2 + (col - k1));
  float4 a = *(const float4*)src;
  float4 b = *(const float4*)(src+4);
  bf16 t[8] = {f2bf(a.x),f2bf(a.y),f2bf(a.z),f2bf(a.w),
               f2bf(b.x),f2bf(b.y),f2bf(b.z),f2bf(b.w)};
  *(uint4*)(dst + e) = *(uint4*)t;
}

__global__ __launch_bounds__(256) void w3_attd_f(
    bf16* __restrict__ w3, const float* __restrict__ attd_w)
{
  long c = (long)blockIdx.x*256 + threadIdx.x;   // 512*2048/8 chunks
  long e = c*8;
  long r = e / 2048; int col = (int)(e % 2048);
  bf16 t[8];
  if (col < 1024){
    const float* src = attd_w + r*1024 + col;
    float4 a = *(const float4*)src;
    float4 b = *(const float4*)(src+4);
    t[0]=f2bf(a.x); t[1]=f2bf(a.y); t[2]=f2bf(a.z); t[3]=f2bf(a.w);
    t[4]=f2bf(b.x); t[5]=f2bf(b.y); t[6]=f2bf(b.z); t[7]=f2bf(b.w);
  } else {
    bf16 z = f2bf(0.f);
#pragma unroll
    for (int u=0;u<8;u++) t[u]=z;
  }
  *(uint4*)(w3 + (4096 + r)*2048 + col) = *(uint4*)t;
}

__global__ __launch_bounds__(256) void attb_kernel(
    const float* __restrict__ a, const float* __restrict__ b, float* __restrict__ o)
{
  int i = blockIdx.x*256 + threadIdx.x;
  if (i < ADIM) o[i] = a[i] + b[i];
}

__global__ __launch_bounds__(256) void embed_kernel(
    const int* __restrict__ seqs, const int* __restrict__ order,
    const float* __restrict__ emb, int t, bf16* __restrict__ x1)
{
  int idx = blockIdx.x*256 + threadIdx.x;   // b*E + e
  int b = idx >> 10, e = idx & 1023;
  int tok = seqs[order[b]*LSEQ + t];
  x1[(long)b*K1 + 3072 + e] = f2bf(emb[(long)tok*EDIM + e]);
}

// ---------------------------------------------------------------------------
// Per-step fused kernels
// ---------------------------------------------------------------------------
__global__ __launch_bounds__(256) void gates1_kernel(
    const float* __restrict__ g, const float* __restrict__ bias,
    const float* __restrict__ h_old, float* __restrict__ h_new,
    float* __restrict__ c, const int* __restrict__ nact, int t,
    bf16* __restrict__ x1, bf16* __restrict__ x2, bf16* __restrict__ x3)
{
  int idx = blockIdx.x*256 + threadIdx.x;
  int b = idx >> 10, d = idx & 1023;
  if (b >= nact[t]) { h_new[idx] = h_old[idx]; return; }  // ping-pong carry copy
  float gi=0,gf=0,gg=0,go=0;
#pragma unroll
  for (int z=0; z<SPLT; z++){
    const float* gz = g + (long)z*BB*G4 + (long)b*G4;
    gi += gz[d]; gf += gz[d+1024]; gg += gz[d+2048]; go += gz[d+3072];
  }
  gi += bias[d]; gf += bias[d+1024]; gg += bias[d+2048]; go += bias[d+3072];
  float cn = sig_(gf)*c[idx] + sig_(gi)*tanh_(gg);
  float hn = sig_(go)*tanh_(cn);
  h_new[idx] = hn;
  c[idx] = cn;
  x1[(long)b*K1 + 4096 + d] = f2bf(hn);   // h1 carry for next-step td GEMM
  x2[(long)b*K2 + 2048 + d] = f2bf(hn);   // h1n into lang GEMM
  x3[(long)b*K3 + d]        = f2bf(hn);   // h1n into ar/q GEMM
}

// blocks [0,1024): gates3 (ar-LSTM);  blocks [1024,1280): scores+softmax+aw
__global__ __launch_bounds__(256) void gates3_attn_kernel(
    const float* __restrict__ g,          // g3: 4 split-K partials, N3 cols
    const float* __restrict__ bias,
    float* __restrict__ arh, float* __restrict__ arc,
    const float* __restrict__ imgatt,     // attf_b+attd_b folded
    const float* __restrict__ att_w, const float* __restrict__ att_b,
    const bf16* __restrict__ feats_bf, const int* __restrict__ order,
    const int* __restrict__ nact, int t,
    bf16* __restrict__ arhn_bf, bf16* __restrict__ x3, bf16* __restrict__ x2)
{
  int bid = blockIdx.x;
  if (bid < 1024) {
    int idx = bid*256 + threadIdx.x;
    int b = idx >> 10, d = idx & 1023;
    if (b >= nact[t]) return;
    float gi=0,gf=0,gg=0,go=0;
#pragma unroll
    for (int z=0; z<4; z++){
      const float* gz = g + (long)z*BB*N3 + (long)b*N3;
      gi += gz[d]; gf += gz[d+1024]; gg += gz[d+2048]; go += gz[d+3072];
    }
    gi += bias[d]; gf += bias[d+1024]; gg += bias[d+2048]; go += bias[d+3072];
    float cn = sig_(gf)*arc[idx] + sig_(gi)*tanh_(gg);
    float hn = sig_(go)*tanh_(cn);
    arh[idx] = hn;
    arc[idx] = cn;
    arhn_bf[idx] = f2bf(hn);                      // -> arl GEMM
    x3[(long)b*K3 + 1024 + d] = f2bf(hn);         // carry for next step
    return;
  }
  int b = bid - 1024;
  if (b >= nact[t]) return;
  __shared__ float qv[ADIM];
  __shared__ float sc[NIMG];
  __shared__ float alpha[NIMG];
  int tid = threadIdx.x;
  {   // q[b] = sum of 4 split-K partials (cols 4096..4607 of g3)
    const float* q0 = g + (long)b*N3 + 4096;
    for (int a = tid; a < ADIM; a += 256)
      qv[a] = q0[a] + q0[(long)BB*N3 + a] + q0[2L*BB*N3 + a] + q0[3L*BB*N3 + a];
  }
  __syncthreads();
  int wv = tid >> 6, ln = tid & 63;
  for (int n = wv; n < NIMG; n += 4){
    const float* ia = imgatt + ((long)b*NIMG + n)*ADIM;
    float s = 0.f;
#pragma unroll
    for (int u=0; u<8; u++){
      int a = u*64 + ln;
      float v = qv[a] + ia[a];
      v = fmaxf(v, 0.f);
      s += v * att_w[a];
    }
    for (int off=32; off; off>>=1) s += __shfl_down(s, off);
    if (ln == 0) sc[n] = s + att_b[0];
  }
  __syncthreads();
  if (tid < 64) {
    float v = (tid < NIMG) ? sc[tid] : -1e30f;
    float m = v;
    for (int off=32; off; off>>=1) m = fmaxf(m, __shfl_down(m, off));
    m = __shfl(m, 0);
    float e = (tid < NIMG) ? __expf(v - m) : 0.f;
    float sum = e;
    for (int off=32; off; off>>=1) sum += __shfl_down(sum, off);
    sum = __shfl(sum, 0);
    if (tid < NIMG) alpha[tid] = e / sum;
  }
  __syncthreads();
  const bf16* fsb = feats_bf + (long)order[b]*NIMG*FDIM;
  int f0 = tid*8;                           // 256*8 == 2048
  float s[8] = {0.f,0.f,0.f,0.f,0.f,0.f,0.f,0.f};
#pragma unroll 4
  for (int n=0; n<NIMG; n++){
    float al = alpha[n];
    bf16 v[8]; *(s8v*)v = *(const s8v*)(fsb + (long)n*FDIM + f0);
#pragma unroll
    for (int u=0;u<8;u++) s[u] += al * bf2f(v[u]);
  }
  bf16 o[8];
#pragma unroll
  for (int u=0;u<8;u++) o[u] = f2bf(s[u]);
  *(uint4*)(x2 + (long)b*K2 + f0) = *(uint4*)o;
}

// blocks [0,1024): gates2 + embed(t+1);  blocks [1024,1280): loss
__global__ __launch_bounds__(256) void gates2_emb_loss_kernel(
    const float* __restrict__ g, const float* __restrict__ bias,
    float* __restrict__ h2s, float* __restrict__ c2s,
    const int* __restrict__ nact, int t,
    bf16* __restrict__ h2n_bf, bf16* __restrict__ x1, bf16* __restrict__ x2,
    const int* __restrict__ seqs, const int* __restrict__ order,
    const float* __restrict__ emb,
    const float* __restrict__ arl_out, const float* __restrict__ h_old,
    const float* __restrict__ bszf, float* __restrict__ loss)
{
  int bid = blockIdx.x;
  if (bid < 1024) {
    int idx = bid*256 + threadIdx.x;
    int b = idx >> 10, d = idx & 1023;
    if (t+1 < TSTEP && b < nact[t+1]) {       // embed for next step
      int tok = seqs[order[b]*LSEQ + (t+1)];
      x1[(long)b*K1 + 3072 + d] = f2bf(emb[(long)tok*EDIM + d]);
    }
    if (b >= nact[t]) return;
    float gi=0,gf=0,gg=0,go=0;
#pragma unroll
    for (int z=0; z<SPLT; z++){
      const float* gz = g + (long)z*BB*G4 + (long)b*G4;
      gi += gz[d]; gf += gz[d+1024]; gg += gz[d+2048]; go += gz[d+3072];
    }
    gi += bias[d]; gf += bias[d+1024]; gg += bias[d+2048]; go += bias[d+3072];
    float cn = sig_(gf)*c2s[idx] + sig_(gi)*tanh_(gg);
    float hn = sig_(go)*tanh_(cn);
    h2s[idx] = hn;
    c2s[idx] = cn;
    h2n_bf[idx] = f2bf(hn);                 // -> vocab GEMM (masked epilogue)
    x1[(long)b*K1 + d]        = f2bf(hn);   // h2 carry for next-step td GEMM
    x2[(long)b*K2 + 3072 + d] = f2bf(hn);   // h2 carry for next-step lang GEMM
    return;
  }
  if (t == 0) return;
  int b = bid - 1024;
  if (b >= nact[t]) return;
  const long SDL = (long)BB*DDIM;
  float s = 0.f;
  for (int d = threadIdx.x; d < DDIM; d += 256) {
    long i = (long)b*DDIM + d;
    float v = arl_out[i] + arl_out[SDL + i] - h_old[i];
    s += v*v;
  }
  __shared__ float red[4];
  for (int off=32; off; off>>=1) s += __shfl_down(s, off);
  if ((threadIdx.x & 63) == 0) red[threadIdx.x >> 6] = s;
  __syncthreads();
  if (threadIdx.x == 0) {
    float tot = red[0]+red[1]+red[2]+red[3];
    atomicAdd(loss, tot * (0.005f / bszf[t]));
  }
}

__global__ void finalize_kernel(const float* __restrict__ loss, float* __restrict__ out){
  if (threadIdx.x == 0) out[(long)BB*TSTEP*VDIM] = *loss;
}

// ---------------------------------------------------------------------------
extern "C" void kernel_launch(void* const* d_in, const int* in_sizes, int n_in,
                              void* d_out, int out_size, void* d_ws, size_t ws_size,
                              hipStream_t stream) {
  const float* feats    = (const float*)d_in[0];
  const int*   seqs     = (const int*)d_in[1];
  const int*   sizesp   = (const int*)d_in[2];
  const float* emb      = (const float*)d_in[3];
  const float* td_wih   = (const float*)d_in[4];
  const float* td_whh   = (const float*)d_in[5];
  const float* td_b     = (const float*)d_in[6];
  const float* lang_wih = (const float*)d_in[7];
  const float* lang_whh = (const float*)d_in[8];
  const float* lang_b   = (const float*)d_in[9];
  const float* attf_w   = (const float*)d_in[10];
  const float* attf_b   = (const float*)d_in[11];
  const float* attd_w   = (const float*)d_in[12];
  const float* attd_b   = (const float*)d_in[13];
  const float* att_w    = (const float*)d_in[14];
  const float* att_b    = (const float*)d_in[15];
  const float* out_w    = (const float*)d_in[16];
  const float* out_b    = (const float*)d_in[17];
  const float* ar_wih   = (const float*)d_in[18];
  const float* ar_whh   = (const float*)d_in[19];
  const float* ar_b     = (const float*)d_in[20];
  const float* arl_w    = (const float*)d_in[21];
  const float* arl_b    = (const float*)d_in[22];
  float* out = (float*)d_out;

  char* p = (char*)d_ws;
  auto alloc = [&](size_t n) -> void* {
    void* r = (void*)p; p += ((n + 255) & ~(size_t)255); return r;
  };
  const long SD = (long)BB*DDIM;   // 262144 floats per state

  int*   order    = (int*)  alloc(BB*4);
  int*   dec      = (int*)  alloc(BB*4);
  float* bszf     = (float*)alloc(TSTEP*4);
  int*   nact     = (int*)  alloc(TSTEP*4);
  int*   rowmap   = (int*)  alloc(BB*NIMG*4);
  float* stateblk = (float*)alloc((7*SD + 64)*4);  // h1A,h1B,c1,h2,c2,arh,arc,loss
  bf16*  W1       = (bf16*) alloc((size_t)G4*K1*2);
  bf16*  W2       = (bf16*) alloc((size_t)G4*K2*2);
  bf16*  W3       = (bf16*) alloc((size_t)N3*K3*2);
  bf16*  feats_bf = (bf16*) alloc((size_t)BB*NIMG*FDIM*2);
  bf16*  attf_bf  = (bf16*) alloc((size_t)ADIM*FDIM*2);
  bf16*  outw_bf  = (bf16*) alloc((size_t)VDIM*DDIM*2);
  bf16*  arlw_bf  = (bf16*) alloc((size_t)DDIM*DDIM*2);
  bf16*  xcat1    = (bf16*) alloc((size_t)BB*K1*2);
  bf16*  xcat2    = (bf16*) alloc((size_t)BB*K2*2);
  bf16*  xcat3    = (bf16*) alloc((size_t)BB*K3*2);
  bf16*  h2n_bf   = (bf16*) alloc((size_t)BB*DDIM*2);
  bf16*  arhn_bf  = (bf16*) alloc((size_t)BB*DDIM*2);
  float* g12      = (float*)alloc((size_t)4*BB*N3*4);     // td/ar/lang partials (max: ar)
  float* arl_out  = (float*)alloc((size_t)SPLTA*BB*DDIM*4);
  float* imgatt   = (float*)alloc((size_t)BB*NIMG*ADIM*4);
  float* attb     = (float*)alloc((size_t)ADIM*4);

  size_t need = (size_t)(p - (char*)d_ws);
  if (need > ws_size) {
    fprintf(stderr, "kernel_launch: ws too small: need %zu have %zu\n", need, ws_size);
    return;
  }

  float* h1A = stateblk;
  float* h1B = stateblk + SD;
  float* c1  = stateblk + 2*SD;
  float* h2s = stateblk + 3*SD;
  float* c2s = stateblk + 4*SD;
  float* arh = stateblk + 5*SD;
  float* arc = stateblk + 6*SD;
  float* loss = stateblk + 7*SD;

  auto mkargs = [](const bf16* A,int lda,const bf16* Bw,int ldb,float* C,long ldc,
                   int M,int Nreal,int Ktot,int ns,const float* bias,
                   const int* rowmap,const int* mask,int nbx,int nby,int tt,int un){
    GArgs g; g.A=A; g.Bw=Bw; g.C=C; g.bias=bias; g.rowmap=rowmap; g.mask=mask;
    g.ldc=ldc; g.lda=lda; g.ldb=ldb; g.M=M; g.Nreal=Nreal; g.Ktot=Ktot; g.nsplit=ns;
    g.nbx=nbx; g.nby=nby; g.tt=tt; g.use_nact=un; return g;
  };

  // ---- setup ----
  sort_kernel<<<1, 256, 0, stream>>>(sizesp, order, dec, bszf, nact, rowmap);
  long nz = 7*SD + 64;
  zero_f32<<<(int)((nz + 255)/256), 256, 0, stream>>>(stateblk, nz);
  long nout = (long)BB*TSTEP*VDIM;   // pre-zero: vocab GEMM skips inactive blocks
  zero_f32<<<(int)((nout + 255)/256), 256, 0, stream>>>(out, nout);
  init_xcat<<<1024, 256, 0, stream>>>(xcat1, xcat2, xcat3);
  favg_kernel<<<2048, 256, 0, stream>>>(feats, order, xcat1);
  f2b_kernel<<<9216, 256, 0, stream>>>(feats,  feats_bf, (long)BB*NIMG*FDIM);
  f2b_kernel<<< 512, 256, 0, stream>>>(attf_w, attf_bf,  (long)ADIM*FDIM);
  f2b_kernel<<<5000, 256, 0, stream>>>(out_w,  outw_bf,  (long)VDIM*DDIM);
  f2b_kernel<<< 512, 256, 0, stream>>>(arl_w,  arlw_bf,  (long)DDIM*DDIM);
  concat2_f<<<10240, 256, 0, stream>>>(W1, td_wih, 4096, td_whh, 1024, 4096);
  concat2_f<<< 8192, 256, 0, stream>>>(W2, lang_wih, 3072, lang_whh, 1024, 4096);
  concat2_f<<< 4096, 256, 0, stream>>>(W3, ar_wih, 1024, ar_whh, 1024, 4096);
  w3_attd_f<<<512, 256, 0, stream>>>(W3, attd_w);
  attb_kernel<<<2, 256, 0, stream>>>(attf_b, attd_b, attb);

  GArgs ia = mkargs(feats_bf, FDIM, attf_bf, FDIM, imgatt, ADIM,
                    BB*NIMG, ADIM, FDIM, 1, attb, rowmap, nullptr, 4, 72, 0, 0);
  gemm_dual<128,128><<<288, 256, 0, stream>>>(ia, ia, 288, nact);

  embed_kernel<<<1024, 256, 0, stream>>>(seqs, order, emb, 0, xcat1);
  GArgs td0 = mkargs(xcat1, K1, W1, K1, g12, G4, BB, G4, K1, SPLT,
                     nullptr, nullptr, nullptr, 32, 2, 0, 1);
  gemm_dual<128,128><<<32*2*SPLT, 256, 0, stream>>>(td0, td0, 32*2*SPLT, nact);

  // ---- recurrence ----
  for (int t = 0; t < TSTEP; t++) {
    float* h1old = (t & 1) ? h1B : h1A;
    float* h1new = (t & 1) ? h1A : h1B;

    gates1_kernel<<<1024, 256, 0, stream>>>(
        g12, td_b, h1old, h1new, c1, nact, t, xcat1, xcat2, xcat3);

    GArgs ar = mkargs(xcat3, K3, W3, K3, g12, N3, BB, N3, K3, 4,
                      nullptr, nullptr, nullptr, 36, 2, t, 1);
    gemm_dual<128,128><<<36*2*4, 256, 0, stream>>>(ar, ar, 36*2*4, nact);

    gates3_attn_kernel<<<1280, 256, 0, stream>>>(
        g12, ar_b, arh, arc, imgatt, att_w, att_b, feats_bf, order,
        nact, t, arhn_bf, xcat3, xcat2);

    GArgs lg = mkargs(xcat2, K2, W2, K2, g12, G4, BB, G4, K2, SPLT,
                      nullptr, nullptr, nullptr, 32, 2, t, 1);
    GArgs al = mkargs(arhn_bf, DDIM, arlw_bf, DDIM, arl_out, DDIM,
                      BB, DDIM, DDIM, SPLTA, arl_b, nullptr, nullptr, 8, 2, t, 1);
    gemm_dual<128,128><<<32*2*SPLT + 8*2*SPLTA, 256, 0, stream>>>(lg, al, 32*2*SPLT, nact);

    gates2_emb_loss_kernel<<<1280, 256, 0, stream>>>(
        g12, lang_b, h2s, c2s, nact, t, h2n_bf, xcat1, xcat2,
        seqs, order, emb, arl_out, h1old, bszf, loss);

    GArgs vo = mkargs(h2n_bf, DDIM, outw_bf, DDIM, out + (long)t*VDIM,
                      (long)TSTEP*VDIM, BB, VDIM, DDIM, 1,
                      out_b, nullptr, dec, 79, 2, t, 1);
    if (t + 1 < TSTEP) {
      GArgs tn = mkargs(xcat1, K1, W1, K1, g12, G4, BB, G4, K1, SPLT,
                        nullptr, nullptr, nullptr, 32, 2, t+1, 1);
      gemm_dual<128,128><<<79*2 + 32*2*SPLT, 256, 0, stream>>>(vo, tn, 79*2, nact);
    } else {
      gemm_dual<128,128><<<79*2, 256, 0, stream>>>(vo, vo, 79*2, nact);
    }
  }

  finalize_kernel<<<1, 64, 0, stream>>>(loss, out);
}